// Round 2
// baseline (1132.355 us; speedup 1.0000x reference)
//
#include <hip/hip_runtime.h>

#define NCOL 64
#define KDIM 128

// ---------------- K1: int degree histograms ----------------
__global__ void hist_kernel(const int* __restrict__ src, const int* __restrict__ dst,
                            int* __restrict__ outcnt, int* __restrict__ incnt, int E) {
    int i = blockIdx.x * blockDim.x + threadIdx.x;
    int stride = gridDim.x * blockDim.x;
    for (int e = i; e < E; e += stride) {
        atomicAdd(&outcnt[src[e]], 1);
        atomicAdd(&incnt[dst[e]], 1);
    }
}

// ---------------- K2: single-block exclusive scan of incnt -> row_start, cursor ----------------
__global__ __launch_bounds__(1024) void scan_kernel(const int* __restrict__ cnt,
                                                    int* __restrict__ row_start,
                                                    int* __restrict__ cursor, int N, int E) {
    __shared__ int wsum[16];
    __shared__ int carry_s;
    int tid = threadIdx.x, lane = tid & 63, wid = tid >> 6;
    if (tid == 0) carry_s = 0;
    __syncthreads();
    for (int base = 0; base < N; base += 1024) {
        int i = base + tid;
        int x = (i < N) ? cnt[i] : 0;
        int inc = x;
#pragma unroll
        for (int off = 1; off < 64; off <<= 1) {
            int t = __shfl_up(inc, off);
            if (lane >= off) inc += t;
        }
        if (lane == 63) wsum[wid] = inc;
        __syncthreads();
        if (wid == 0) {
            int s = (lane < 16) ? wsum[lane] : 0;
#pragma unroll
            for (int off = 1; off < 16; off <<= 1) {
                int t = __shfl_up(s, off);
                if (lane >= off) s += t;
            }
            if (lane < 16) wsum[lane] = s;
        }
        __syncthreads();
        int carry = carry_s;
        int woff = (wid > 0) ? wsum[wid - 1] : 0;
        int excl = carry + woff + inc - x;
        if (i < N) { row_start[i] = excl; cursor[i] = excl; }
        __syncthreads();
        if (tid == 0) carry_s = carry + wsum[15];
        __syncthreads();
    }
    if (tid == 0) row_start[N] = E;
}

// ---------------- K3: reorder edges into dst-sorted order (only src needed) ----------------
__global__ void reorder_kernel(const int* __restrict__ src, const int* __restrict__ dst,
                               int* __restrict__ cursor, int* __restrict__ ssrc, int E) {
    int i = blockIdx.x * blockDim.x + threadIdx.x;
    int stride = gridDim.x * blockDim.x;
    for (int e = i; e < E; e += stride) {
        int pos = atomicAdd(&cursor[dst[e]], 1);
        ssrc[pos] = src[e];
    }
}

// ---------------- K4: dual matvec: h = (feat*norm_src)@W ; res = relu(feat@RW + rb) ----------------
__global__ __launch_bounds__(256) void matmul_kernel(
    const float* __restrict__ feat, const float* __restrict__ W,
    const float* __restrict__ RW, const float* __restrict__ res_b,
    const int* __restrict__ outcnt,
    float* __restrict__ h, float* __restrict__ res_out, int N) {
    __shared__ float Wt[NCOL][KDIM];
    __shared__ float RWt[NCOL][KDIM];
    int tid = threadIdx.x;
    for (int idx = tid; idx < KDIM * NCOL; idx += 256) {
        int k = idx >> 6, c = idx & 63;
        int a = (((k >> 2) ^ (c & 7)) << 2) | (k & 3);
        Wt[c][a] = W[idx];
        RWt[c][a] = RW[idx];
    }
    __syncthreads();

    int c = tid & 63;
    int w = tid >> 6;
    int base = blockIdx.x * 32 + w * 8;

    int nidx[8];
#pragma unroll
    for (int u = 0; u < 8; ++u) {
        int n = base + u;
        nidx[u] = n < N ? n : 0;
    }

    float hacc[8], racc[8];
#pragma unroll
    for (int u = 0; u < 8; ++u) { hacc[u] = 0.0f; racc[u] = 0.0f; }

    const int swz = (c & 7) << 2;
#pragma unroll 8
    for (int k4 = 0; k4 < KDIM / 4; ++k4) {
        float4 wv = *(const float4*)&Wt[c][(k4 << 2) ^ swz];
        float4 rv = *(const float4*)&RWt[c][(k4 << 2) ^ swz];
#pragma unroll
        for (int u = 0; u < 8; ++u) {
            float4 f = *(const float4*)&feat[(size_t)nidx[u] * KDIM + (k4 << 2)];
            hacc[u] += f.x * wv.x + f.y * wv.y + f.z * wv.z + f.w * wv.w;
            racc[u] += f.x * rv.x + f.y * rv.y + f.z * rv.z + f.w * rv.w;
        }
    }

    float rb = res_b[c];
#pragma unroll
    for (int u = 0; u < 8; ++u) {
        int n = base + u;
        if (n < N) {
            float ns = rsqrtf(fmaxf((float)outcnt[n], 1.0f));
            h[(size_t)n * NCOL + c] = hacc[u] * ns;
            float r = racc[u] + rb;
            res_out[(size_t)n * NCOL + c] = r > 0.0f ? r : 0.0f;
        }
    }
}

// ---------------- K5: gather + finalize: y = relu(sum(h[src])*norm_dst + b) + res ; BN partials ----------------
__global__ __launch_bounds__(256) void gather_kernel(
    const int* __restrict__ row_start, const int* __restrict__ ssrc,
    const float* __restrict__ h, const float* __restrict__ b,
    float* __restrict__ y, float* __restrict__ stats, int N) {
    int tid = threadIdx.x, lane = tid & 63, wid = tid >> 6;
    int nw = gridDim.x * 4;
    float bc = b[lane];
    float lsum = 0.0f, lsq = 0.0f;
    for (int d = blockIdx.x * 4 + wid; d < N; d += nw) {
        int s0 = row_start[d], s1 = row_start[d + 1];
        float acc = 0.0f;
        for (int base = s0; base < s1; base += 64) {
            int cnt = min(64, s1 - base);
            int myi = (lane < cnt) ? ssrc[base + lane] : 0;
#pragma unroll 4
            for (int j = 0; j < cnt; ++j) {
                int s = __shfl(myi, j);
                acc += h[(size_t)s * NCOL + lane];
            }
        }
        float nd = rsqrtf(fmaxf((float)(s1 - s0), 1.0f));
        float conv = acc * nd + bc;
        conv = conv > 0.0f ? conv : 0.0f;
        float v = conv + y[(size_t)d * NCOL + lane];
        y[(size_t)d * NCOL + lane] = v;
        lsum += v;
        lsq += v * v;
    }
    __shared__ float red[512];
    red[tid] = lsum;
    red[256 + tid] = lsq;
    __syncthreads();
    if (tid < 64) {
        float s = red[tid] + red[tid + 64] + red[tid + 128] + red[tid + 192];
        float q = red[256 + tid] + red[256 + tid + 64] + red[256 + tid + 128] + red[256 + tid + 192];
        unsafeAtomicAdd(&stats[tid], s);
        unsafeAtomicAdd(&stats[64 + tid], q);
    }
}

// ---------------- K6: BN scale/shift ----------------
__global__ void bnparam_kernel(const float* __restrict__ gamma, const float* __restrict__ beta,
                               float* __restrict__ stats, float invN) {
    int c = threadIdx.x;
    float mean = stats[c] * invN;
    float var = stats[64 + c] * invN - mean * mean;
    float s = gamma[c] * rsqrtf(var + 1e-5f);
    stats[128 + c] = s;
    stats[192 + c] = beta[c] - mean * s;
}

// ---------------- K7: BN apply (in place, float4) ----------------
__global__ __launch_bounds__(256) void apply_kernel(float* __restrict__ y,
                                                    const float* __restrict__ stats, int total4) {
    int i = blockIdx.x * blockDim.x + threadIdx.x;
    int stride = gridDim.x * blockDim.x;
    float4* y4 = (float4*)y;
    for (; i < total4; i += stride) {
        float4 v = y4[i];
        int cbase = (i & 15) << 2;
        float4 s = *(const float4*)&stats[128 + cbase];
        float4 t = *(const float4*)&stats[192 + cbase];
        v.x = v.x * s.x + t.x;
        v.y = v.y * s.y + t.y;
        v.z = v.z * s.z + t.z;
        v.w = v.w * s.w + t.w;
        y4[i] = v;
    }
}

extern "C" void kernel_launch(void* const* d_in, const int* in_sizes, int n_in,
                              void* d_out, int out_size, void* d_ws, size_t ws_size,
                              hipStream_t stream) {
    const float* feat  = (const float*)d_in[0];
    const int*   src   = (const int*)d_in[1];
    const int*   dst   = (const int*)d_in[2];
    const float* W     = (const float*)d_in[3];
    const float* b     = (const float*)d_in[4];
    const float* RW    = (const float*)d_in[5];
    const float* rb    = (const float*)d_in[6];
    const float* gamma = (const float*)d_in[7];
    const float* beta  = (const float*)d_in[8];

    int N = in_sizes[0] / KDIM;
    int E = in_sizes[1];
    float* out = (float*)d_out;

    // workspace layout
    char* wsb = (char*)d_ws;
    float* h        = (float*)wsb;                         wsb += (size_t)N * NCOL * 4;
    int*   ssrc     = (int*)wsb;                           wsb += (size_t)E * 4;
    int*   outcnt   = (int*)wsb;                           wsb += (size_t)N * 4;
    int*   incnt    = (int*)wsb;                           wsb += (size_t)N * 4;
    float* stats    = (float*)wsb;                         wsb += 256 * 4;
    int*   row_start= (int*)wsb;                           wsb += (size_t)(N + 1) * 4;
    int*   cursor   = (int*)wsb;

    // zero outcnt, incnt, stats (contiguous)
    hipMemsetAsync(outcnt, 0, ((size_t)2 * N + 256) * 4, stream);

    hist_kernel<<<1024, 256, 0, stream>>>(src, dst, outcnt, incnt, E);
    scan_kernel<<<1, 1024, 0, stream>>>(incnt, row_start, cursor, N, E);
    matmul_kernel<<<(N + 31) / 32, 256, 0, stream>>>(feat, W, RW, rb, outcnt, h, out, N);
    reorder_kernel<<<1024, 256, 0, stream>>>(src, dst, cursor, ssrc, E);
    gather_kernel<<<(N + 3) / 4, 256, 0, stream>>>(row_start, ssrc, h, b, out, stats, N);
    bnparam_kernel<<<1, 64, 0, stream>>>(gamma, beta, stats, 1.0f / (float)N);
    apply_kernel<<<2048, 256, 0, stream>>>(out, stats, (N * NCOL) / 4);
}

// Round 3
// 611.946 us; speedup vs baseline: 1.8504x; 1.8504x over previous
//
#include <hip/hip_runtime.h>

#define NCOL 64
#define KDIM 128

// ---------------- K1: int degree histograms ----------------
__global__ void hist_kernel(const int* __restrict__ src, const int* __restrict__ dst,
                            int* __restrict__ outcnt, int* __restrict__ incnt, int E) {
    int i = blockIdx.x * blockDim.x + threadIdx.x;
    int stride = gridDim.x * blockDim.x;
    for (int e = i; e < E; e += stride) {
        atomicAdd(&outcnt[src[e]], 1);
        atomicAdd(&incnt[dst[e]], 1);
    }
}

// ---------------- K2: single-block exclusive scan of incnt -> row_start, cursor ----------------
__global__ __launch_bounds__(1024) void scan_kernel(const int* __restrict__ cnt,
                                                    int* __restrict__ row_start,
                                                    int* __restrict__ cursor, int N, int E) {
    __shared__ int wsum[16];
    __shared__ int carry_s;
    int tid = threadIdx.x, lane = tid & 63, wid = tid >> 6;
    if (tid == 0) carry_s = 0;
    __syncthreads();
    for (int base = 0; base < N; base += 1024) {
        int i = base + tid;
        int x = (i < N) ? cnt[i] : 0;
        int inc = x;
#pragma unroll
        for (int off = 1; off < 64; off <<= 1) {
            int t = __shfl_up(inc, off);
            if (lane >= off) inc += t;
        }
        if (lane == 63) wsum[wid] = inc;
        __syncthreads();
        if (wid == 0) {
            int s = (lane < 16) ? wsum[lane] : 0;
#pragma unroll
            for (int off = 1; off < 16; off <<= 1) {
                int t = __shfl_up(s, off);
                if (lane >= off) s += t;
            }
            if (lane < 16) wsum[lane] = s;
        }
        __syncthreads();
        int carry = carry_s;
        int woff = (wid > 0) ? wsum[wid - 1] : 0;
        int excl = carry + woff + inc - x;
        if (i < N) { row_start[i] = excl; cursor[i] = excl; }
        __syncthreads();
        if (tid == 0) carry_s = carry + wsum[15];
        __syncthreads();
    }
    if (tid == 0) row_start[N] = E;
}

// ---------------- K3: reorder edges into dst-sorted order (only src needed) ----------------
__global__ void reorder_kernel(const int* __restrict__ src, const int* __restrict__ dst,
                               int* __restrict__ cursor, int* __restrict__ ssrc, int E) {
    int i = blockIdx.x * blockDim.x + threadIdx.x;
    int stride = gridDim.x * blockDim.x;
    for (int e = i; e < E; e += stride) {
        int pos = atomicAdd(&cursor[dst[e]], 1);
        ssrc[pos] = src[e];
    }
}

// ---------------- K4: dual matvec: h = (feat*norm_src)@W ; res = relu(feat@RW + rb) ----------------
__global__ __launch_bounds__(256) void matmul_kernel(
    const float* __restrict__ feat, const float* __restrict__ W,
    const float* __restrict__ RW, const float* __restrict__ res_b,
    const int* __restrict__ outcnt,
    float* __restrict__ h, float* __restrict__ res_out, int N) {
    __shared__ float Wt[NCOL][KDIM];
    __shared__ float RWt[NCOL][KDIM];
    int tid = threadIdx.x;
    for (int idx = tid; idx < KDIM * NCOL; idx += 256) {
        int k = idx >> 6, c = idx & 63;
        int a = (((k >> 2) ^ (c & 7)) << 2) | (k & 3);
        Wt[c][a] = W[idx];
        RWt[c][a] = RW[idx];
    }
    __syncthreads();

    int c = tid & 63;
    int w = tid >> 6;
    int base = blockIdx.x * 32 + w * 8;

    int nidx[8];
#pragma unroll
    for (int u = 0; u < 8; ++u) {
        int n = base + u;
        nidx[u] = n < N ? n : 0;
    }

    float hacc[8], racc[8];
#pragma unroll
    for (int u = 0; u < 8; ++u) { hacc[u] = 0.0f; racc[u] = 0.0f; }

    const int swz = (c & 7) << 2;
#pragma unroll 8
    for (int k4 = 0; k4 < KDIM / 4; ++k4) {
        float4 wv = *(const float4*)&Wt[c][(k4 << 2) ^ swz];
        float4 rv = *(const float4*)&RWt[c][(k4 << 2) ^ swz];
#pragma unroll
        for (int u = 0; u < 8; ++u) {
            float4 f = *(const float4*)&feat[(size_t)nidx[u] * KDIM + (k4 << 2)];
            hacc[u] += f.x * wv.x + f.y * wv.y + f.z * wv.z + f.w * wv.w;
            racc[u] += f.x * rv.x + f.y * rv.y + f.z * rv.z + f.w * rv.w;
        }
    }

    float rb = res_b[c];
#pragma unroll
    for (int u = 0; u < 8; ++u) {
        int n = base + u;
        if (n < N) {
            float ns = rsqrtf(fmaxf((float)outcnt[n], 1.0f));
            h[(size_t)n * NCOL + c] = hacc[u] * ns;
            float r = racc[u] + rb;
            res_out[(size_t)n * NCOL + c] = r > 0.0f ? r : 0.0f;
        }
    }
}

// ---------------- K5: edge-parallel gather + finalize ----------------
// Wave = 16 edges x 4 lanes. q = lane&3 owns 16 cols of the h row as 4 float4s
// at byte offset q*16 + st*64. Row sum via shfl_xor butterfly over the 16
// edge-groups (offsets 4,8,16,32). Lanes 0..3 finalize + write + BN partials.
__global__ __launch_bounds__(256) void gather_kernel(
    const int* __restrict__ row_start, const int* __restrict__ ssrc,
    const float* __restrict__ h, const float* __restrict__ b,
    float* __restrict__ y, float* __restrict__ stats, int N) {
    int tid = threadIdx.x, lane = tid & 63, wid = tid >> 6;
    int q = lane & 3;
    int esub = lane >> 2;           // edge sub-index 0..15
    int wave = blockIdx.x * 4 + wid;
    int nwaves = gridDim.x * 4;

    // per-lane bias fragment (cols st*16 + q*4 .. +4)
    float4 bc[4];
#pragma unroll
    for (int st = 0; st < 4; ++st) bc[st] = *(const float4*)&b[st * 16 + q * 4];

    float4 bnsum[4], bnsq[4];
#pragma unroll
    for (int st = 0; st < 4; ++st) {
        bnsum[st] = make_float4(0.f, 0.f, 0.f, 0.f);
        bnsq[st] = make_float4(0.f, 0.f, 0.f, 0.f);
    }

    for (int d = wave; d < N; d += nwaves) {
        int s0 = row_start[d], s1 = row_start[d + 1];
        float4 acc[4];
#pragma unroll
        for (int st = 0; st < 4; ++st) acc[st] = make_float4(0.f, 0.f, 0.f, 0.f);

        for (int base = s0; base < s1; base += 16) {
            int e = base + esub;
            if (e < s1) {
                int s = ssrc[e];
                const float* hp = h + (size_t)s * NCOL + q * 4;
                float4 v0 = *(const float4*)(hp);
                float4 v1 = *(const float4*)(hp + 16);
                float4 v2 = *(const float4*)(hp + 32);
                float4 v3 = *(const float4*)(hp + 48);
                acc[0].x += v0.x; acc[0].y += v0.y; acc[0].z += v0.z; acc[0].w += v0.w;
                acc[1].x += v1.x; acc[1].y += v1.y; acc[1].z += v1.z; acc[1].w += v1.w;
                acc[2].x += v2.x; acc[2].y += v2.y; acc[2].z += v2.z; acc[2].w += v2.w;
                acc[3].x += v3.x; acc[3].y += v3.y; acc[3].z += v3.z; acc[3].w += v3.w;
            }
        }

        // butterfly: reduce over the 16 edge-groups (lane bits 2..5)
#pragma unroll
        for (int off = 4; off <= 32; off <<= 1) {
#pragma unroll
            for (int st = 0; st < 4; ++st) {
                acc[st].x += __shfl_xor(acc[st].x, off);
                acc[st].y += __shfl_xor(acc[st].y, off);
                acc[st].z += __shfl_xor(acc[st].z, off);
                acc[st].w += __shfl_xor(acc[st].w, off);
            }
        }

        if (lane < 4) {
            float nd = rsqrtf(fmaxf((float)(s1 - s0), 1.0f));
#pragma unroll
            for (int st = 0; st < 4; ++st) {
                float* yp = &y[(size_t)d * NCOL + st * 16 + q * 4];
                float4 r = *(const float4*)yp;
                float4 v;
                v.x = fmaxf(acc[st].x * nd + bc[st].x, 0.f) + r.x;
                v.y = fmaxf(acc[st].y * nd + bc[st].y, 0.f) + r.y;
                v.z = fmaxf(acc[st].z * nd + bc[st].z, 0.f) + r.z;
                v.w = fmaxf(acc[st].w * nd + bc[st].w, 0.f) + r.w;
                *(float4*)yp = v;
                bnsum[st].x += v.x; bnsum[st].y += v.y; bnsum[st].z += v.z; bnsum[st].w += v.w;
                bnsq[st].x += v.x * v.x; bnsq[st].y += v.y * v.y;
                bnsq[st].z += v.z * v.z; bnsq[st].w += v.w * v.w;
            }
        }
    }

    // block-level BN reduction: wave w, lane q<4 -> LDS, then 128 atomics
    __shared__ float bnred[4][128];
    if (lane < 4) {
#pragma unroll
        for (int st = 0; st < 4; ++st) {
            *(float4*)&bnred[wid][st * 16 + q * 4] = bnsum[st];
            *(float4*)&bnred[wid][64 + st * 16 + q * 4] = bnsq[st];
        }
    }
    __syncthreads();
    if (tid < 128) {
        float v = bnred[0][tid] + bnred[1][tid] + bnred[2][tid] + bnred[3][tid];
        unsafeAtomicAdd(&stats[(tid >> 6) * 64 + (tid & 63)], v);
    }
}

// ---------------- K6: BN scale/shift ----------------
__global__ void bnparam_kernel(const float* __restrict__ gamma, const float* __restrict__ beta,
                               float* __restrict__ stats, float invN) {
    int c = threadIdx.x;
    float mean = stats[c] * invN;
    float var = stats[64 + c] * invN - mean * mean;
    float s = gamma[c] * rsqrtf(var + 1e-5f);
    stats[128 + c] = s;
    stats[192 + c] = beta[c] - mean * s;
}

// ---------------- K7: BN apply (in place, float4) ----------------
__global__ __launch_bounds__(256) void apply_kernel(float* __restrict__ y,
                                                    const float* __restrict__ stats, int total4) {
    int i = blockIdx.x * blockDim.x + threadIdx.x;
    int stride = gridDim.x * blockDim.x;
    float4* y4 = (float4*)y;
    for (; i < total4; i += stride) {
        float4 v = y4[i];
        int cbase = (i & 15) << 2;
        float4 s = *(const float4*)&stats[128 + cbase];
        float4 t = *(const float4*)&stats[192 + cbase];
        v.x = v.x * s.x + t.x;
        v.y = v.y * s.y + t.y;
        v.z = v.z * s.z + t.z;
        v.w = v.w * s.w + t.w;
        y4[i] = v;
    }
}

extern "C" void kernel_launch(void* const* d_in, const int* in_sizes, int n_in,
                              void* d_out, int out_size, void* d_ws, size_t ws_size,
                              hipStream_t stream) {
    const float* feat  = (const float*)d_in[0];
    const int*   src   = (const int*)d_in[1];
    const int*   dst   = (const int*)d_in[2];
    const float* W     = (const float*)d_in[3];
    const float* b     = (const float*)d_in[4];
    const float* RW    = (const float*)d_in[5];
    const float* rb    = (const float*)d_in[6];
    const float* gamma = (const float*)d_in[7];
    const float* beta  = (const float*)d_in[8];

    int N = in_sizes[0] / KDIM;
    int E = in_sizes[1];
    float* out = (float*)d_out;

    // workspace layout
    char* wsb = (char*)d_ws;
    float* h        = (float*)wsb;                         wsb += (size_t)N * NCOL * 4;
    int*   ssrc     = (int*)wsb;                           wsb += (size_t)E * 4;
    int*   outcnt   = (int*)wsb;                           wsb += (size_t)N * 4;
    int*   incnt    = (int*)wsb;                           wsb += (size_t)N * 4;
    float* stats    = (float*)wsb;                         wsb += 256 * 4;
    int*   row_start= (int*)wsb;                           wsb += (size_t)(N + 1) * 4;
    int*   cursor   = (int*)wsb;

    // zero outcnt, incnt, stats (contiguous)
    hipMemsetAsync(outcnt, 0, ((size_t)2 * N + 256) * 4, stream);

    hist_kernel<<<1024, 256, 0, stream>>>(src, dst, outcnt, incnt, E);
    scan_kernel<<<1, 1024, 0, stream>>>(incnt, row_start, cursor, N, E);
    matmul_kernel<<<(N + 31) / 32, 256, 0, stream>>>(feat, W, RW, rb, outcnt, h, out, N);
    reorder_kernel<<<1024, 256, 0, stream>>>(src, dst, cursor, ssrc, E);
    gather_kernel<<<2048, 256, 0, stream>>>(row_start, ssrc, h, b, out, stats, N);
    bnparam_kernel<<<1, 64, 0, stream>>>(gamma, beta, stats, 1.0f / (float)N);
    apply_kernel<<<2048, 256, 0, stream>>>(out, stats, (N * NCOL) / 4);
}

// Round 4
// 483.884 us; speedup vs baseline: 2.3401x; 1.2647x over previous
//
#include <hip/hip_runtime.h>

#define NCOL 64
#define KDIM 128

typedef short bf16x8 __attribute__((ext_vector_type(8)));
typedef float f32x4 __attribute__((ext_vector_type(4)));

__device__ __forceinline__ unsigned short f2bf(float f) {
    unsigned int u = __float_as_uint(f);
    return (unsigned short)((u + 0x7fffu + ((u >> 16) & 1u)) >> 16);
}
__device__ __forceinline__ float bflo(unsigned int u) { return __uint_as_float(u << 16); }
__device__ __forceinline__ float bfhi(unsigned int u) { return __uint_as_float(u & 0xffff0000u); }

// ---------------- K1: int degree histograms ----------------
__global__ void hist_kernel(const int* __restrict__ src, const int* __restrict__ dst,
                            int* __restrict__ outcnt, int* __restrict__ incnt, int E) {
    int i = blockIdx.x * blockDim.x + threadIdx.x;
    int stride = gridDim.x * blockDim.x;
    for (int e = i; e < E; e += stride) {
        atomicAdd(&outcnt[src[e]], 1);
        atomicAdd(&incnt[dst[e]], 1);
    }
}

// ---------------- K2: single-block exclusive scan ----------------
__global__ __launch_bounds__(1024) void scan_kernel(const int* __restrict__ cnt,
                                                    int* __restrict__ row_start,
                                                    int* __restrict__ cursor, int N, int E) {
    __shared__ int wsum[16];
    __shared__ int carry_s;
    int tid = threadIdx.x, lane = tid & 63, wid = tid >> 6;
    if (tid == 0) carry_s = 0;
    __syncthreads();
    for (int base = 0; base < N; base += 1024) {
        int i = base + tid;
        int x = (i < N) ? cnt[i] : 0;
        int inc = x;
#pragma unroll
        for (int off = 1; off < 64; off <<= 1) {
            int t = __shfl_up(inc, off);
            if (lane >= off) inc += t;
        }
        if (lane == 63) wsum[wid] = inc;
        __syncthreads();
        if (wid == 0) {
            int s = (lane < 16) ? wsum[lane] : 0;
#pragma unroll
            for (int off = 1; off < 16; off <<= 1) {
                int t = __shfl_up(s, off);
                if (lane >= off) s += t;
            }
            if (lane < 16) wsum[lane] = s;
        }
        __syncthreads();
        int carry = carry_s;
        int woff = (wid > 0) ? wsum[wid - 1] : 0;
        int excl = carry + woff + inc - x;
        if (i < N) { row_start[i] = excl; cursor[i] = excl; }
        __syncthreads();
        if (tid == 0) carry_s = carry + wsum[15];
        __syncthreads();
    }
    if (tid == 0) row_start[N] = E;
}

// ---------------- K3: reorder edges into dst-sorted order ----------------
__global__ void reorder_kernel(const int* __restrict__ src, const int* __restrict__ dst,
                               int* __restrict__ cursor, int* __restrict__ ssrc, int E) {
    int i = blockIdx.x * blockDim.x + threadIdx.x;
    int stride = gridDim.x * blockDim.x;
    for (int e = i; e < E; e += stride) {
        int pos = atomicAdd(&cursor[dst[e]], 1);
        ssrc[pos] = src[e];
    }
}

// ---------------- K4: MFMA dual GEMM ----------------
// wave = 16-node tile. B-frags (W, RW) pre-transposed to fragment layout in LDS
// (linear frag addressing: frag[((mat*4+kc)*4+ct)*64 + lane], 16B/lane -> conflict-free).
// A: lane loads 8 consecutive f32 of row (lane&15) at k = kc*32 + (lane>>4)*8, packs bf16.
// D-layout: col = ct*16 + (lane&15), rows = tb + (lane>>4)*4 + r.
__global__ __launch_bounds__(256) void matmul_mfma(
    const float* __restrict__ feat, const float* __restrict__ W,
    const float* __restrict__ RW, const float* __restrict__ res_b,
    const int* __restrict__ outcnt,
    unsigned short* __restrict__ hb, float* __restrict__ y, int N) {
    __shared__ bf16x8 Bf[2048];   // 32 KB: [mat][kc][ct][lane]
    int tid = threadIdx.x;
    for (int idx = tid; idx < 2048; idx += 256) {
        int mat = idx >> 10;
        int kc = (idx >> 8) & 3;
        int ct = (idx >> 6) & 3;
        int l = idx & 63;
        const float* Wp = mat ? RW : W;
        int kbase = kc * 32 + (l >> 4) * 8;
        int col = ct * 16 + (l & 15);
        bf16x8 t;
#pragma unroll
        for (int j = 0; j < 8; ++j)
            t[j] = (short)f2bf(Wp[(size_t)(kbase + j) * NCOL + col]);
        Bf[idx] = t;
    }
    __syncthreads();

    int lane = tid & 63;
    int wid = tid >> 6;
    int wave = blockIdx.x * 4 + wid;
    int nwaves = gridDim.x * 4;
    int ntiles = (N + 15) >> 4;
    int c16 = lane & 15, kg = lane >> 4;

    float rbv[4];
#pragma unroll
    for (int ct = 0; ct < 4; ++ct) rbv[ct] = res_b[ct * 16 + c16];

    for (int tile = wave; tile < ntiles; tile += nwaves) {
        int tb = tile << 4;
        f32x4 acch[4], accr[4];
#pragma unroll
        for (int ct = 0; ct < 4; ++ct) {
            acch[ct] = (f32x4){0.f, 0.f, 0.f, 0.f};
            accr[ct] = (f32x4){0.f, 0.f, 0.f, 0.f};
        }

        int arow = tb + c16; if (arow >= N) arow = N - 1;
        const float* fp = feat + (size_t)arow * KDIM + kg * 8;
#pragma unroll
        for (int kc = 0; kc < 4; ++kc) {
            float4 a0 = *(const float4*)(fp + kc * 32);
            float4 a1 = *(const float4*)(fp + kc * 32 + 4);
            bf16x8 af;
            af[0] = (short)f2bf(a0.x); af[1] = (short)f2bf(a0.y);
            af[2] = (short)f2bf(a0.z); af[3] = (short)f2bf(a0.w);
            af[4] = (short)f2bf(a1.x); af[5] = (short)f2bf(a1.y);
            af[6] = (short)f2bf(a1.z); af[7] = (short)f2bf(a1.w);
#pragma unroll
            for (int ct = 0; ct < 4; ++ct) {
                acch[ct] = __builtin_amdgcn_mfma_f32_16x16x32_bf16(
                    af, Bf[(kc * 4 + ct) * 64 + lane], acch[ct], 0, 0, 0);
                accr[ct] = __builtin_amdgcn_mfma_f32_16x16x32_bf16(
                    af, Bf[1024 + (kc * 4 + ct) * 64 + lane], accr[ct], 0, 0, 0);
            }
        }

        float nrm[4];
#pragma unroll
        for (int r = 0; r < 4; ++r) {
            int rw = tb + kg * 4 + r; if (rw >= N) rw = N - 1;
            nrm[r] = rsqrtf(fmaxf((float)outcnt[rw], 1.0f));
        }
#pragma unroll
        for (int ct = 0; ct < 4; ++ct) {
#pragma unroll
            for (int r = 0; r < 4; ++r) {
                int row = tb + kg * 4 + r;
                if (row < N) {
                    size_t off = (size_t)row * NCOL + ct * 16 + c16;
                    hb[off] = f2bf(acch[ct][r] * nrm[r]);
                    y[off] = fmaxf(accr[ct][r] + rbv[ct], 0.0f);
                }
            }
        }
    }
}

// ---------------- K5: edge-parallel gather (bf16 h) + finalize ----------------
__global__ __launch_bounds__(256) void gather_kernel(
    const int* __restrict__ row_start, const int* __restrict__ ssrc,
    const unsigned short* __restrict__ hb, const float* __restrict__ b,
    float* __restrict__ y, float* __restrict__ stats, int N) {
    int tid = threadIdx.x, lane = tid & 63, wid = tid >> 6;
    int q = lane & 3;
    int esub = lane >> 2;
    int wave = blockIdx.x * 4 + wid;
    int nwaves = gridDim.x * 4;

    float4 bc[4];
#pragma unroll
    for (int k = 0; k < 4; ++k) bc[k] = *(const float4*)&b[q * 16 + k * 4];

    float4 bnsum[4], bnsq[4];
#pragma unroll
    for (int k = 0; k < 4; ++k) {
        bnsum[k] = make_float4(0.f, 0.f, 0.f, 0.f);
        bnsq[k] = make_float4(0.f, 0.f, 0.f, 0.f);
    }

    for (int d = wave; d < N; d += nwaves) {
        int s0 = row_start[d], s1 = row_start[d + 1];
        float4 acc[4];
#pragma unroll
        for (int k = 0; k < 4; ++k) acc[k] = make_float4(0.f, 0.f, 0.f, 0.f);

        for (int base = s0; base < s1; base += 16) {
            int e = base + esub;
            if (e < s1) {
                int s = ssrc[e];
                const unsigned short* hp = hb + (size_t)s * NCOL + q * 16;
                uint4 r0 = *(const uint4*)hp;
                uint4 r1 = *(const uint4*)(hp + 8);
                acc[0].x += bflo(r0.x); acc[0].y += bfhi(r0.x);
                acc[0].z += bflo(r0.y); acc[0].w += bfhi(r0.y);
                acc[1].x += bflo(r0.z); acc[1].y += bfhi(r0.z);
                acc[1].z += bflo(r0.w); acc[1].w += bfhi(r0.w);
                acc[2].x += bflo(r1.x); acc[2].y += bfhi(r1.x);
                acc[2].z += bflo(r1.y); acc[2].w += bfhi(r1.y);
                acc[3].x += bflo(r1.z); acc[3].y += bfhi(r1.z);
                acc[3].z += bflo(r1.w); acc[3].w += bfhi(r1.w);
            }
        }

#pragma unroll
        for (int off = 4; off <= 32; off <<= 1) {
#pragma unroll
            for (int k = 0; k < 4; ++k) {
                acc[k].x += __shfl_xor(acc[k].x, off);
                acc[k].y += __shfl_xor(acc[k].y, off);
                acc[k].z += __shfl_xor(acc[k].z, off);
                acc[k].w += __shfl_xor(acc[k].w, off);
            }
        }

        if (lane < 4) {
            float nd = rsqrtf(fmaxf((float)(s1 - s0), 1.0f));
#pragma unroll
            for (int k = 0; k < 4; ++k) {
                float* yp = &y[(size_t)d * NCOL + q * 16 + k * 4];
                float4 r = *(const float4*)yp;
                float4 v;
                v.x = fmaxf(acc[k].x * nd + bc[k].x, 0.f) + r.x;
                v.y = fmaxf(acc[k].y * nd + bc[k].y, 0.f) + r.y;
                v.z = fmaxf(acc[k].z * nd + bc[k].z, 0.f) + r.z;
                v.w = fmaxf(acc[k].w * nd + bc[k].w, 0.f) + r.w;
                *(float4*)yp = v;
                bnsum[k].x += v.x; bnsum[k].y += v.y; bnsum[k].z += v.z; bnsum[k].w += v.w;
                bnsq[k].x += v.x * v.x; bnsq[k].y += v.y * v.y;
                bnsq[k].z += v.z * v.z; bnsq[k].w += v.w * v.w;
            }
        }
    }

    __shared__ float bnred[4][128];
    if (lane < 4) {
#pragma unroll
        for (int k = 0; k < 4; ++k) {
            *(float4*)&bnred[wid][q * 16 + k * 4] = bnsum[k];
            *(float4*)&bnred[wid][64 + q * 16 + k * 4] = bnsq[k];
        }
    }
    __syncthreads();
    if (tid < 128) {
        float v = bnred[0][tid] + bnred[1][tid] + bnred[2][tid] + bnred[3][tid];
        unsafeAtomicAdd(&stats[tid], v);
    }
}

// ---------------- K6: BN scale/shift ----------------
__global__ void bnparam_kernel(const float* __restrict__ gamma, const float* __restrict__ beta,
                               float* __restrict__ stats, float invN) {
    int c = threadIdx.x;
    float mean = stats[c] * invN;
    float var = stats[64 + c] * invN - mean * mean;
    float s = gamma[c] * rsqrtf(var + 1e-5f);
    stats[128 + c] = s;
    stats[192 + c] = beta[c] - mean * s;
}

// ---------------- K7: BN apply (in place, float4) ----------------
__global__ __launch_bounds__(256) void apply_kernel(float* __restrict__ y,
                                                    const float* __restrict__ stats, int total4) {
    int i = blockIdx.x * blockDim.x + threadIdx.x;
    int stride = gridDim.x * blockDim.x;
    float4* y4 = (float4*)y;
    for (; i < total4; i += stride) {
        float4 v = y4[i];
        int cbase = (i & 15) << 2;
        float4 s = *(const float4*)&stats[128 + cbase];
        float4 t = *(const float4*)&stats[192 + cbase];
        v.x = v.x * s.x + t.x;
        v.y = v.y * s.y + t.y;
        v.z = v.z * s.z + t.z;
        v.w = v.w * s.w + t.w;
        y4[i] = v;
    }
}

extern "C" void kernel_launch(void* const* d_in, const int* in_sizes, int n_in,
                              void* d_out, int out_size, void* d_ws, size_t ws_size,
                              hipStream_t stream) {
    const float* feat  = (const float*)d_in[0];
    const int*   src   = (const int*)d_in[1];
    const int*   dst   = (const int*)d_in[2];
    const float* W     = (const float*)d_in[3];
    const float* b     = (const float*)d_in[4];
    const float* RW    = (const float*)d_in[5];
    const float* rb    = (const float*)d_in[6];
    const float* gamma = (const float*)d_in[7];
    const float* beta  = (const float*)d_in[8];

    int N = in_sizes[0] / KDIM;
    int E = in_sizes[1];
    float* out = (float*)d_out;

    // workspace layout
    char* wsb = (char*)d_ws;
    unsigned short* hb = (unsigned short*)wsb;             wsb += (size_t)N * NCOL * 2;
    int*   ssrc     = (int*)wsb;                           wsb += (size_t)E * 4;
    int*   outcnt   = (int*)wsb;                           wsb += (size_t)N * 4;
    int*   incnt    = (int*)wsb;                           wsb += (size_t)N * 4;
    float* stats    = (float*)wsb;                         wsb += 256 * 4;
    int*   row_start= (int*)wsb;                           wsb += (size_t)(N + 1) * 4;
    int*   cursor   = (int*)wsb;

    // zero outcnt, incnt, stats (contiguous)
    hipMemsetAsync(outcnt, 0, ((size_t)2 * N + 256) * 4, stream);

    hist_kernel<<<1024, 256, 0, stream>>>(src, dst, outcnt, incnt, E);
    scan_kernel<<<1, 1024, 0, stream>>>(incnt, row_start, cursor, N, E);
    matmul_mfma<<<512, 256, 0, stream>>>(feat, W, RW, rb, outcnt, hb, out, N);
    reorder_kernel<<<1024, 256, 0, stream>>>(src, dst, cursor, ssrc, E);
    gather_kernel<<<2048, 256, 0, stream>>>(row_start, ssrc, hb, b, out, stats, N);
    bnparam_kernel<<<1, 64, 0, stream>>>(gamma, beta, stats, 1.0f / (float)N);
    apply_kernel<<<2048, 256, 0, stream>>>(out, stats, (N * NCOL) / 4);
}

// Round 5
// 289.850 us; speedup vs baseline: 3.9067x; 1.6694x over previous
//
#include <hip/hip_runtime.h>

#define NCOL 64
#define KDIM 128
#define NB 512          // max coarse buckets (dst>>8, N<=131072)
#define CH 4096         // edges per partition chunk

typedef short bf16x8 __attribute__((ext_vector_type(8)));
typedef float f32x4 __attribute__((ext_vector_type(4)));

__device__ __forceinline__ unsigned short f2bf(float f) {
    unsigned int u = __float_as_uint(f);
    return (unsigned short)((u + 0x7fffu + ((u >> 16) & 1u)) >> 16);
}
__device__ __forceinline__ float bflo(unsigned int u) { return __uint_as_float(u << 16); }
__device__ __forceinline__ float bfhi(unsigned int u) { return __uint_as_float(u & 0xffff0000u); }

// ---------------- K1: coarse bucket hist (LDS) + outcnt hist ----------------
__global__ __launch_bounds__(256) void coarse_hist(const int* __restrict__ src,
                                                   const int* __restrict__ dst,
                                                   int* __restrict__ outcnt,
                                                   int* __restrict__ bcnt, int E) {
    __shared__ int lh[NB];
    int tid = threadIdx.x;
    for (int i = tid; i < NB; i += 256) lh[i] = 0;
    __syncthreads();
    int i = blockIdx.x * blockDim.x + tid;
    int stride = gridDim.x * blockDim.x;
    for (int e = i; e < E; e += stride) {
        atomicAdd(&outcnt[src[e]], 1);
        atomicAdd(&lh[dst[e] >> 8], 1);
    }
    __syncthreads();
    for (int k = tid; k < NB; k += 256) {
        int c = lh[k];
        if (c) atomicAdd(&bcnt[k], c);
    }
}

// ---------------- K2: scan bucket counts -> bbase, bcur ----------------
__global__ __launch_bounds__(256) void bucket_scan(const int* __restrict__ bcnt,
                                                   int* __restrict__ bbase, int* __restrict__ bcur,
                                                   int* __restrict__ row_start, int N, int E) {
    __shared__ int wsum[8];
    int tid = threadIdx.x, lane = tid & 63, wv = tid >> 6;
    int a = bcnt[tid], b = bcnt[tid + 256];
    int ia = a, ib = b;
#pragma unroll
    for (int off = 1; off < 64; off <<= 1) {
        int t = __shfl_up(ia, off); if (lane >= off) ia += t;
        int u = __shfl_up(ib, off); if (lane >= off) ib += u;
    }
    if (lane == 63) { wsum[wv] = ia; wsum[4 + wv] = ib; }
    __syncthreads();
    if (tid == 0) { int run = 0; for (int i = 0; i < 8; ++i) { int t = wsum[i]; wsum[i] = run; run += t; } }
    __syncthreads();
    int ea = wsum[wv] + ia - a;
    int eb = wsum[4 + wv] + ib - b;
    bbase[tid] = ea; bcur[tid] = ea;
    bbase[tid + 256] = eb; bcur[tid + 256] = eb;
    if (tid == 0) row_start[N] = E;
}

// ---------------- K3: partition edges into coarse buckets (coalesced writes) ----------------
__global__ __launch_bounds__(256) void partition_kernel(
    const int* __restrict__ src, const int* __restrict__ dst,
    int* __restrict__ bcur, uint2* __restrict__ pairs, int E) {
    __shared__ int hist[NB];
    __shared__ int lbase[NB];
    __shared__ int gbase[NB];
    __shared__ int lcur[NB];
    __shared__ uint2 sp[CH];   // 32 KB
    __shared__ int wsum[8];

    int tid = threadIdx.x, lane = tid & 63, wv = tid >> 6;
    int c0 = blockIdx.x * CH;
    int cnt = min(CH, E - c0);

    for (int i = tid; i < NB; i += 256) hist[i] = 0;
    __syncthreads();
    for (int i = tid; i < cnt; i += 256)
        atomicAdd(&hist[dst[c0 + i] >> 8], 1);
    __syncthreads();

    // exclusive scan of hist[0..511] with 256 threads
    {
        int a = hist[tid], b = hist[tid + 256];
        int ia = a, ib = b;
#pragma unroll
        for (int off = 1; off < 64; off <<= 1) {
            int t = __shfl_up(ia, off); if (lane >= off) ia += t;
            int u = __shfl_up(ib, off); if (lane >= off) ib += u;
        }
        if (lane == 63) { wsum[wv] = ia; wsum[4 + wv] = ib; }
        __syncthreads();
        if (tid == 0) { int run = 0; for (int i = 0; i < 8; ++i) { int t = wsum[i]; wsum[i] = run; run += t; } }
        __syncthreads();
        lbase[tid] = wsum[wv] + ia - a;
        lbase[tid + 256] = wsum[4 + wv] + ib - b;
    }
    __syncthreads();

    // reserve global space per bucket; init local cursors
    for (int k = tid; k < NB; k += 256) {
        int c = hist[k];
        gbase[k] = c ? atomicAdd(&bcur[k], c) : 0;
        lcur[k] = lbase[k];
    }
    __syncthreads();

    // rescatter chunk into bucket-ordered LDS (re-read global, L2-hot)
    for (int i = tid; i < cnt; i += 256) {
        int s = src[c0 + i], d = dst[c0 + i];
        int p = atomicAdd(&lcur[d >> 8], 1);
        sp[p] = make_uint2((unsigned)s, (unsigned)d);
    }
    __syncthreads();

    // linear write-out: consecutive i within a bucket -> consecutive global addrs
    for (int i = tid; i < cnt; i += 256) {
        uint2 p = sp[i];
        int k = (int)(p.y >> 8);
        pairs[gbase[k] + (i - lbase[k])] = p;
    }
}

// ---------------- K4: fine counting sort within bucket -> ssrc + row_start ----------------
__global__ __launch_bounds__(256) void fine_kernel(
    const uint2* __restrict__ pairs, const int* __restrict__ bbase,
    int* __restrict__ row_start, int* __restrict__ ssrc, int E, int nbuck, int N) {
    __shared__ int hist[256];
    __shared__ int cur[256];
    __shared__ int wsum[4];
    int k = blockIdx.x;
    int tid = threadIdx.x, lane = tid & 63, wv = tid >> 6;
    int b0 = bbase[k];
    int b1 = (k + 1 < nbuck) ? bbase[k + 1] : E;

    hist[tid] = 0;
    __syncthreads();
    for (int i = b0 + tid; i < b1; i += 256)
        atomicAdd(&hist[pairs[i].y & 255], 1);
    __syncthreads();

    // exclusive scan of 256
    int x = hist[tid], inc = x;
#pragma unroll
    for (int off = 1; off < 64; off <<= 1) {
        int t = __shfl_up(inc, off); if (lane >= off) inc += t;
    }
    if (lane == 63) wsum[wv] = inc;
    __syncthreads();
    if (tid == 0) { int run = 0; for (int i = 0; i < 4; ++i) { int t = wsum[i]; wsum[i] = run; run += t; } }
    __syncthreads();
    int excl = wsum[wv] + inc - x;

    int d = (k << 8) + tid;
    if (d < N) row_start[d] = b0 + excl;
    cur[tid] = b0 + excl;
    __syncthreads();

    for (int i = b0 + tid; i < b1; i += 256) {
        uint2 p = pairs[i];
        int pos = atomicAdd(&cur[p.y & 255], 1);
        ssrc[pos] = (int)p.x;
    }
}

// ---------------- K5: MFMA dual GEMM ----------------
__global__ __launch_bounds__(256) void matmul_mfma(
    const float* __restrict__ feat, const float* __restrict__ W,
    const float* __restrict__ RW, const float* __restrict__ res_b,
    const int* __restrict__ outcnt,
    unsigned short* __restrict__ hb, float* __restrict__ y, int N) {
    __shared__ bf16x8 Bf[2048];   // 32 KB
    int tid = threadIdx.x;
    for (int idx = tid; idx < 2048; idx += 256) {
        int mat = idx >> 10;
        int kc = (idx >> 8) & 3;
        int ct = (idx >> 6) & 3;
        int l = idx & 63;
        const float* Wp = mat ? RW : W;
        int kbase = kc * 32 + (l >> 4) * 8;
        int col = ct * 16 + (l & 15);
        bf16x8 t;
#pragma unroll
        for (int j = 0; j < 8; ++j)
            t[j] = (short)f2bf(Wp[(size_t)(kbase + j) * NCOL + col]);
        Bf[idx] = t;
    }
    __syncthreads();

    int lane = tid & 63;
    int wid = tid >> 6;
    int wave = blockIdx.x * 4 + wid;
    int nwaves = gridDim.x * 4;
    int ntiles = (N + 15) >> 4;
    int c16 = lane & 15, kg = lane >> 4;

    float rbv[4];
#pragma unroll
    for (int ct = 0; ct < 4; ++ct) rbv[ct] = res_b[ct * 16 + c16];

    for (int tile = wave; tile < ntiles; tile += nwaves) {
        int tb = tile << 4;
        f32x4 acch[4], accr[4];
#pragma unroll
        for (int ct = 0; ct < 4; ++ct) {
            acch[ct] = (f32x4){0.f, 0.f, 0.f, 0.f};
            accr[ct] = (f32x4){0.f, 0.f, 0.f, 0.f};
        }

        int arow = tb + c16; if (arow >= N) arow = N - 1;
        const float* fp = feat + (size_t)arow * KDIM + kg * 8;
#pragma unroll
        for (int kc = 0; kc < 4; ++kc) {
            float4 a0 = *(const float4*)(fp + kc * 32);
            float4 a1 = *(const float4*)(fp + kc * 32 + 4);
            bf16x8 af;
            af[0] = (short)f2bf(a0.x); af[1] = (short)f2bf(a0.y);
            af[2] = (short)f2bf(a0.z); af[3] = (short)f2bf(a0.w);
            af[4] = (short)f2bf(a1.x); af[5] = (short)f2bf(a1.y);
            af[6] = (short)f2bf(a1.z); af[7] = (short)f2bf(a1.w);
#pragma unroll
            for (int ct = 0; ct < 4; ++ct) {
                acch[ct] = __builtin_amdgcn_mfma_f32_16x16x32_bf16(
                    af, Bf[(kc * 4 + ct) * 64 + lane], acch[ct], 0, 0, 0);
                accr[ct] = __builtin_amdgcn_mfma_f32_16x16x32_bf16(
                    af, Bf[1024 + (kc * 4 + ct) * 64 + lane], accr[ct], 0, 0, 0);
            }
        }

        float nrm[4];
#pragma unroll
        for (int r = 0; r < 4; ++r) {
            int rw = tb + kg * 4 + r; if (rw >= N) rw = N - 1;
            nrm[r] = rsqrtf(fmaxf((float)outcnt[rw], 1.0f));
        }
#pragma unroll
        for (int ct = 0; ct < 4; ++ct) {
#pragma unroll
            for (int r = 0; r < 4; ++r) {
                int row = tb + kg * 4 + r;
                if (row < N) {
                    size_t off = (size_t)row * NCOL + ct * 16 + c16;
                    hb[off] = f2bf(acch[ct][r] * nrm[r]);
                    y[off] = fmaxf(accr[ct][r] + rbv[ct], 0.0f);
                }
            }
        }
    }
}

// ---------------- K6: edge-parallel gather (bf16 h) + finalize ----------------
__global__ __launch_bounds__(256) void gather_kernel(
    const int* __restrict__ row_start, const int* __restrict__ ssrc,
    const unsigned short* __restrict__ hb, const float* __restrict__ b,
    float* __restrict__ y, float* __restrict__ stats, int N) {
    int tid = threadIdx.x, lane = tid & 63, wid = tid >> 6;
    int q = lane & 3;
    int esub = lane >> 2;
    int wave = blockIdx.x * 4 + wid;
    int nwaves = gridDim.x * 4;

    float4 bc[4];
#pragma unroll
    for (int k = 0; k < 4; ++k) bc[k] = *(const float4*)&b[q * 16 + k * 4];

    float4 bnsum[4], bnsq[4];
#pragma unroll
    for (int k = 0; k < 4; ++k) {
        bnsum[k] = make_float4(0.f, 0.f, 0.f, 0.f);
        bnsq[k] = make_float4(0.f, 0.f, 0.f, 0.f);
    }

    for (int d = wave; d < N; d += nwaves) {
        int s0 = row_start[d], s1 = row_start[d + 1];
        float4 acc[4];
#pragma unroll
        for (int k = 0; k < 4; ++k) acc[k] = make_float4(0.f, 0.f, 0.f, 0.f);

        for (int base = s0; base < s1; base += 16) {
            int e = base + esub;
            if (e < s1) {
                int s = ssrc[e];
                const unsigned short* hp = hb + (size_t)s * NCOL + q * 16;
                uint4 r0 = *(const uint4*)hp;
                uint4 r1 = *(const uint4*)(hp + 8);
                acc[0].x += bflo(r0.x); acc[0].y += bfhi(r0.x);
                acc[0].z += bflo(r0.y); acc[0].w += bfhi(r0.y);
                acc[1].x += bflo(r0.z); acc[1].y += bfhi(r0.z);
                acc[1].z += bflo(r0.w); acc[1].w += bfhi(r0.w);
                acc[2].x += bflo(r1.x); acc[2].y += bfhi(r1.x);
                acc[2].z += bflo(r1.y); acc[2].w += bfhi(r1.y);
                acc[3].x += bflo(r1.z); acc[3].y += bfhi(r1.z);
                acc[3].z += bflo(r1.w); acc[3].w += bfhi(r1.w);
            }
        }

#pragma unroll
        for (int off = 4; off <= 32; off <<= 1) {
#pragma unroll
            for (int k = 0; k < 4; ++k) {
                acc[k].x += __shfl_xor(acc[k].x, off);
                acc[k].y += __shfl_xor(acc[k].y, off);
                acc[k].z += __shfl_xor(acc[k].z, off);
                acc[k].w += __shfl_xor(acc[k].w, off);
            }
        }

        if (lane < 4) {
            float nd = rsqrtf(fmaxf((float)(s1 - s0), 1.0f));
#pragma unroll
            for (int k = 0; k < 4; ++k) {
                float* yp = &y[(size_t)d * NCOL + q * 16 + k * 4];
                float4 r = *(const float4*)yp;
                float4 v;
                v.x = fmaxf(acc[k].x * nd + bc[k].x, 0.f) + r.x;
                v.y = fmaxf(acc[k].y * nd + bc[k].y, 0.f) + r.y;
                v.z = fmaxf(acc[k].z * nd + bc[k].z, 0.f) + r.z;
                v.w = fmaxf(acc[k].w * nd + bc[k].w, 0.f) + r.w;
                *(float4*)yp = v;
                bnsum[k].x += v.x; bnsum[k].y += v.y; bnsum[k].z += v.z; bnsum[k].w += v.w;
                bnsq[k].x += v.x * v.x; bnsq[k].y += v.y * v.y;
                bnsq[k].z += v.z * v.z; bnsq[k].w += v.w * v.w;
            }
        }
    }

    __shared__ float bnred[4][128];
    if (lane < 4) {
#pragma unroll
        for (int k = 0; k < 4; ++k) {
            *(float4*)&bnred[wid][q * 16 + k * 4] = bnsum[k];
            *(float4*)&bnred[wid][64 + q * 16 + k * 4] = bnsq[k];
        }
    }
    __syncthreads();
    if (tid < 128) {
        float v = bnred[0][tid] + bnred[1][tid] + bnred[2][tid] + bnred[3][tid];
        unsafeAtomicAdd(&stats[tid], v);
    }
}

// ---------------- K7: BN scale/shift ----------------
__global__ void bnparam_kernel(const float* __restrict__ gamma, const float* __restrict__ beta,
                               float* __restrict__ stats, float invN) {
    int c = threadIdx.x;
    float mean = stats[c] * invN;
    float var = stats[64 + c] * invN - mean * mean;
    float s = gamma[c] * rsqrtf(var + 1e-5f);
    stats[128 + c] = s;
    stats[192 + c] = beta[c] - mean * s;
}

// ---------------- K8: BN apply (in place, float4) ----------------
__global__ __launch_bounds__(256) void apply_kernel(float* __restrict__ y,
                                                    const float* __restrict__ stats, int total4) {
    int i = blockIdx.x * blockDim.x + threadIdx.x;
    int stride = gridDim.x * blockDim.x;
    float4* y4 = (float4*)y;
    for (; i < total4; i += stride) {
        float4 v = y4[i];
        int cbase = (i & 15) << 2;
        float4 s = *(const float4*)&stats[128 + cbase];
        float4 t = *(const float4*)&stats[192 + cbase];
        v.x = v.x * s.x + t.x;
        v.y = v.y * s.y + t.y;
        v.z = v.z * s.z + t.z;
        v.w = v.w * s.w + t.w;
        y4[i] = v;
    }
}

extern "C" void kernel_launch(void* const* d_in, const int* in_sizes, int n_in,
                              void* d_out, int out_size, void* d_ws, size_t ws_size,
                              hipStream_t stream) {
    const float* feat  = (const float*)d_in[0];
    const int*   src   = (const int*)d_in[1];
    const int*   dst   = (const int*)d_in[2];
    const float* W     = (const float*)d_in[3];
    const float* b     = (const float*)d_in[4];
    const float* RW    = (const float*)d_in[5];
    const float* rb    = (const float*)d_in[6];
    const float* gamma = (const float*)d_in[7];
    const float* beta  = (const float*)d_in[8];

    int N = in_sizes[0] / KDIM;
    int E = in_sizes[1];
    float* out = (float*)d_out;
    int nbuck = (N + 255) >> 8;   // assumes N <= 131072

    // workspace layout
    char* wsb = (char*)d_ws;
    unsigned short* hb = (unsigned short*)wsb;             wsb += (size_t)N * NCOL * 2;
    uint2* pairs    = (uint2*)wsb;                         wsb += (size_t)E * 8;
    int*   ssrc     = (int*)wsb;                           wsb += (size_t)E * 4;
    int*   row_start= (int*)wsb;                           wsb += (size_t)(N + 1) * 4;
    int*   outcnt   = (int*)wsb;                           wsb += (size_t)N * 4;
    float* stats    = (float*)wsb;                         wsb += 256 * 4;
    int*   bcnt     = (int*)wsb;                           wsb += NB * 4;
    int*   bbase    = (int*)wsb;                           wsb += NB * 4;
    int*   bcur     = (int*)wsb;

    // zero outcnt | stats | bcnt (contiguous)
    hipMemsetAsync(outcnt, 0, ((size_t)N + 256 + NB) * 4, stream);

    coarse_hist<<<1024, 256, 0, stream>>>(src, dst, outcnt, bcnt, E);
    bucket_scan<<<1, 256, 0, stream>>>(bcnt, bbase, bcur, row_start, N, E);
    matmul_mfma<<<512, 256, 0, stream>>>(feat, W, RW, rb, outcnt, hb, out, N);
    partition_kernel<<<(E + CH - 1) / CH, 256, 0, stream>>>(src, dst, bcur, pairs, E);
    fine_kernel<<<nbuck, 256, 0, stream>>>(pairs, bbase, row_start, ssrc, E, nbuck, N);
    gather_kernel<<<2048, 256, 0, stream>>>(row_start, ssrc, hb, b, out, stats, N);
    bnparam_kernel<<<1, 64, 0, stream>>>(gamma, beta, stats, 1.0f / (float)N);
    apply_kernel<<<2048, 256, 0, stream>>>(out, stats, (N * NCOL) / 4);
}